// Round 1
// baseline (40.053 us; speedup 1.0000x reference)
//
#include <hip/hip_runtime.h>
#include <math.h>

// Problem constants (from reference)
#define B 2048
#define F 26
#define C 64
#define E 64
#define D 13
#define SPARSE_W (F * (C + 1) - 1)   // 1689

// One wave (64 lanes) per sample.
// Pairwise: 4 groups of 16 lanes; group g covers c = g*16 .. g*16+15,
// lane t (0..15) holds float4 covering e = 4t..4t+3.
__global__ __launch_bounds__(256) void dfm_kernel(
    const int*   __restrict__ sparse,   // (B, 1689) int32
    const float* __restrict__ dense,    // (B, 13)
    const float* __restrict__ lin_emb,  // (F, C, 1) -> F*C floats
    const float* __restrict__ emb_tab,  // (F, C, E) floats
    const float* __restrict__ lin_W,    // (F+D, 1)
    const float* __restrict__ lin_b,    // (1,)
    float*       __restrict__ out)      // (B, 1)
{
    const int lane = threadIdx.x & 63;
    const int wv   = threadIdx.x >> 6;
    const int b    = blockIdx.x * 4 + wv;
    if (b >= B) return;

    const int g = lane >> 4;   // group 0..3
    const int t = lane & 15;   // float4 slot within a row (row = 64 floats = 16 float4)

    const float4* __restrict__ emb4 = reinterpret_cast<const float4*>(emb_tab);

    float4 s  = make_float4(0.f, 0.f, 0.f, 0.f);
    float4 sq = make_float4(0.f, 0.f, 0.f, 0.f);
    float  lin = 0.f;

    const int sbase = b * SPARSE_W;

    for (int f = 0; f < F; ++f) {
        // coalesced: lane c loads idx[b, f, c]
        int idxreg = sparse[sbase + f * (C + 1) + lane];

        // linear term, per-feature weight folded in (lane == c)
        lin = fmaf(lin_W[f], lin_emb[f * C + idxreg], lin);

        const float4* rowbase = emb4 + (size_t)(f * C) * 16 + t;
        #pragma unroll
        for (int cc = 0; cc < 16; ++cc) {
            const int c   = g * 16 + cc;
            const int idx = __shfl(idxreg, c);     // broadcast index for this group's c
            float4 w = rowbase[idx * 16];
            s.x += w.x; s.y += w.y; s.z += w.z; s.w += w.w;
            sq.x = fmaf(w.x, w.x, sq.x);
            sq.y = fmaf(w.y, w.y, sq.y);
            sq.z = fmaf(w.z, w.z, sq.z);
            sq.w = fmaf(w.w, w.w, sq.w);
        }
    }

    // dense part of the linear term (lanes 0..12)
    if (lane < D) lin = fmaf(dense[b * D + lane], lin_W[F + lane], lin);

    // full-wave reduction of the linear accumulator
    #pragma unroll
    for (int m = 32; m >= 1; m >>= 1) lin += __shfl_xor(lin, m);

    // group-combine s (need full s[e] before squaring): sum across groups (lane bits 4,5)
    #pragma unroll
    for (int m = 16; m <= 32; m <<= 1) {
        s.x += __shfl_xor(s.x, m);
        s.y += __shfl_xor(s.y, m);
        s.z += __shfl_xor(s.z, m);
        s.w += __shfl_xor(s.w, m);
    }

    // sum of squares term: sq is linear in contributions -> full 64-lane scalar reduce
    float sql = sq.x + sq.y + sq.z + sq.w;
    #pragma unroll
    for (int m = 32; m >= 1; m >>= 1) sql += __shfl_xor(sql, m);

    // sum_e s_total[e]^2 : groups now identical, reduce over t (bits 0..3)
    float s2 = s.x * s.x + s.y * s.y + s.z * s.z + s.w * s.w;
    #pragma unroll
    for (int m = 8; m >= 1; m >>= 1) s2 += __shfl_xor(s2, m);

    if (lane == 0) {
        const float pair = 0.5f * (s2 - sql);
        const float x = lin + lin_b[0] + pair;
        out[b] = 1.f / (1.f + expf(-x));
    }
}

extern "C" void kernel_launch(void* const* d_in, const int* in_sizes, int n_in,
                              void* d_out, int out_size, void* d_ws, size_t ws_size,
                              hipStream_t stream) {
    const int*   sparse  = (const int*)  d_in[0];
    const float* dense   = (const float*)d_in[1];
    const float* lin_emb = (const float*)d_in[2];
    const float* emb_tab = (const float*)d_in[3];
    const float* lin_W   = (const float*)d_in[4];
    const float* lin_b   = (const float*)d_in[5];
    float* out = (float*)d_out;

    // 4 samples (waves) per 256-thread block
    dim3 grid((B + 3) / 4), block(256);
    hipLaunchKernelGGL(dfm_kernel, grid, block, 0, stream,
                       sparse, dense, lin_emb, emb_tab, lin_W, lin_b, out);
}

// Round 2
// 29.473 us; speedup vs baseline: 1.3590x; 1.3590x over previous
//
#include <hip/hip_runtime.h>
#include <hip/hip_bf16.h>
#include <math.h>

// Problem constants
#define B 2048
#define F 26
#define C 64
#define E 64
#define D 13
#define SPARSE_W (F * (C + 1) - 1)   // 1689
#define K (F * C)                    // 1664
#define N2 128                       // 64 S cols | 64 SQ cols
#define KSPLIT 4
#define KCH (K / KSPLIT)             // 416
#define KSTEPS (KCH / 32)            // 13

typedef short short8 __attribute__((ext_vector_type(8)));
typedef float f32x4  __attribute__((ext_vector_type(4)));

// ws layout (bytes)
#define CNT_OFF 0
#define BT_OFF  ((size_t)B * K * 2)                   // 6,815,744
#define LIN_OFF (BT_OFF + (size_t)K * N2 * 2)         // +425,984
#define PART_OFF (LIN_OFF + (size_t)B * 4)            // +8,192
#define WS_NEED (PART_OFF + (size_t)KSPLIT * B * N2 * 4)  // ~11.44 MB

// ---------------------------------------------------------------------------
// Kernel 1: build Bt[n][k] bf16, n<64: emb[k,e=n]; n>=64: emb[k,e=n-64]^2
// One block per feature f: transpose 64x64 slab via LDS.
__global__ __launch_bounds__(256) void prep_bt_kernel(
    const float* __restrict__ emb_tab, __hip_bfloat16* __restrict__ bt)
{
    __shared__ float tile[64][65];
    const int f = blockIdx.x;
    const float* src = emb_tab + (size_t)f * 4096;   // [v][e]
    for (int i = threadIdx.x; i < 4096; i += 256)
        tile[i >> 6][i & 63] = src[i];
    __syncthreads();
    const int v  = threadIdx.x & 63;
    const int ns = threadIdx.x >> 6;   // 0..3 -> n group of 32
    for (int it = 0; it < 32; ++it) {
        const int n = ns * 32 + it;    // 0..127
        float val = tile[v][n & 63];
        if (n >= 64) val = val * val;
        bt[(size_t)n * K + f * 64 + v] = __float2bfloat16(val);
    }
}

// ---------------------------------------------------------------------------
// Kernel 2: per-sample histogram (Count bf16) + full linear term.
// One block per sample; wave w handles features f = w, w+4, ...
__global__ __launch_bounds__(256) void hist_lin_kernel(
    const int*   __restrict__ sparse,
    const float* __restrict__ dense,
    const float* __restrict__ lin_emb,
    const float* __restrict__ lin_W,
    const float* __restrict__ lin_b,
    __hip_bfloat16* __restrict__ count,
    float* __restrict__ lin_out)
{
    __shared__ int   hist[4][64];
    __shared__ float linp[4];
    const int lane = threadIdx.x & 63;
    const int w    = threadIdx.x >> 6;
    const int b    = blockIdx.x;

    float lin = 0.f;
    for (int f = w; f < F; f += 4) {
        const int idx = sparse[b * SPARSE_W + f * (C + 1) + lane];
        hist[w][lane] = 0;
        asm volatile("s_waitcnt lgkmcnt(0)" ::: "memory");
        atomicAdd(&hist[w][idx], 1);
        asm volatile("s_waitcnt lgkmcnt(0)" ::: "memory");
        const int cnt = hist[w][lane];
        count[(size_t)b * K + f * 64 + lane] = __float2bfloat16((float)cnt);
        lin = fmaf(lin_W[f], lin_emb[f * 64 + idx], lin);
    }
    #pragma unroll
    for (int m = 32; m >= 1; m >>= 1) lin += __shfl_xor(lin, m);
    if (lane == 0) linp[w] = lin;
    __syncthreads();
    if (w == 0) {
        float val = (lane < 4) ? linp[lane] : 0.f;
        if (lane < D) val = fmaf(dense[b * D + lane], lin_W[F + lane], val);
        #pragma unroll
        for (int m = 32; m >= 1; m >>= 1) val += __shfl_xor(val, m);
        if (lane == 0) lin_out[b] = val + lin_b[0];
    }
}

// ---------------------------------------------------------------------------
// Kernel 3: GEMM partials. C_part[s] += Count[32 rows] x Bt^T (K-chunk s).
// Block: 4 waves; wave w -> cols [w*32, w*32+32). blockIdx: mt = >>2, s = &3.
// mfma_f32_16x16x32_bf16; A lane: row=l&15, k=(l>>4)*8+j (contig 16B);
// B lane: col=l&15, same k grouping; C/D: col=l&15, row=(l>>4)*4+r (m89).
__global__ __launch_bounds__(256) void gemm_kernel(
    const __hip_bfloat16* __restrict__ count,
    const __hip_bfloat16* __restrict__ bt,
    float* __restrict__ part)
{
    const int lane = threadIdx.x & 63;
    const int w    = threadIdx.x >> 6;
    const int mt   = blockIdx.x >> 2;
    const int s    = blockIdx.x & 3;

    const int kbase = s * KCH + ((lane >> 4) * 8);
    const short* cb = (const short*)count;
    const short* bb = (const short*)bt;
    const short* pa0 = cb + (size_t)(mt * 32 + (lane & 15)) * K + kbase;
    const short* pa1 = pa0 + 16 * K;
    const short* pb0 = bb + (size_t)(w * 32 + (lane & 15)) * K + kbase;
    const short* pb1 = pb0 + 16 * K;

    f32x4 acc00 = {0.f, 0.f, 0.f, 0.f};
    f32x4 acc01 = {0.f, 0.f, 0.f, 0.f};
    f32x4 acc10 = {0.f, 0.f, 0.f, 0.f};
    f32x4 acc11 = {0.f, 0.f, 0.f, 0.f};

    #pragma unroll
    for (int kk = 0; kk < KSTEPS; ++kk) {
        const int o = kk * 32;
        short8 a0 = *(const short8*)(pa0 + o);
        short8 a1 = *(const short8*)(pa1 + o);
        short8 b0 = *(const short8*)(pb0 + o);
        short8 b1 = *(const short8*)(pb1 + o);
        acc00 = __builtin_amdgcn_mfma_f32_16x16x32_bf16(a0, b0, acc00, 0, 0, 0);
        acc01 = __builtin_amdgcn_mfma_f32_16x16x32_bf16(a0, b1, acc01, 0, 0, 0);
        acc10 = __builtin_amdgcn_mfma_f32_16x16x32_bf16(a1, b0, acc10, 0, 0, 0);
        acc11 = __builtin_amdgcn_mfma_f32_16x16x32_bf16(a1, b1, acc11, 0, 0, 0);
    }

    float* pp = part + (size_t)s * B * N2;
    const int r0 = mt * 32 + ((lane >> 4) * 4);
    const int c0 = w * 32 + (lane & 15);
    #pragma unroll
    for (int r = 0; r < 4; ++r) {
        pp[(size_t)(r0 + r) * N2 + c0]           = acc00[r];
        pp[(size_t)(r0 + r) * N2 + c0 + 16]      = acc01[r];
        pp[(size_t)(r0 + 16 + r) * N2 + c0]      = acc10[r];
        pp[(size_t)(r0 + 16 + r) * N2 + c0 + 16] = acc11[r];
    }
}

// ---------------------------------------------------------------------------
// Kernel 4: reduce K-split partials, pairwise epilogue, sigmoid.
// One wave per sample. lane<32: S cols (2 each) -> s^2; lane>=32: SQ -> -sq.
__global__ __launch_bounds__(256) void reduce_kernel(
    const float* __restrict__ part,
    const float* __restrict__ lin,
    float* __restrict__ out)
{
    const int lane = threadIdx.x & 63;
    const int w    = threadIdx.x >> 6;
    const int b    = blockIdx.x * 4 + w;

    const float2* p2 = (const float2*)part;
    float2 acc = {0.f, 0.f};
    #pragma unroll
    for (int s = 0; s < KSPLIT; ++s) {
        float2 v = p2[((size_t)s * B + b) * 64 + lane];
        acc.x += v.x; acc.y += v.y;
    }
    float contrib = (lane < 32) ? (acc.x * acc.x + acc.y * acc.y)
                                : -(acc.x + acc.y);
    #pragma unroll
    for (int m = 32; m >= 1; m >>= 1) contrib += __shfl_xor(contrib, m);
    if (lane == 0) {
        const float x = lin[b] + 0.5f * contrib;
        out[b] = 1.f / (1.f + expf(-x));
    }
}

// ---------------------------------------------------------------------------
// Fallback (round-1 kernel) if ws is too small for the GEMM path.
__global__ __launch_bounds__(256) void dfm_fallback(
    const int*   __restrict__ sparse,
    const float* __restrict__ dense,
    const float* __restrict__ lin_emb,
    const float* __restrict__ emb_tab,
    const float* __restrict__ lin_W,
    const float* __restrict__ lin_b,
    float*       __restrict__ out)
{
    const int lane = threadIdx.x & 63;
    const int wv   = threadIdx.x >> 6;
    const int b    = blockIdx.x * 4 + wv;
    if (b >= B) return;
    const int g = lane >> 4;
    const int t = lane & 15;
    const float4* emb4 = reinterpret_cast<const float4*>(emb_tab);
    float4 s  = make_float4(0.f, 0.f, 0.f, 0.f);
    float4 sq = make_float4(0.f, 0.f, 0.f, 0.f);
    float  lin = 0.f;
    const int sbase = b * SPARSE_W;
    for (int f = 0; f < F; ++f) {
        int idxreg = sparse[sbase + f * (C + 1) + lane];
        lin = fmaf(lin_W[f], lin_emb[f * C + idxreg], lin);
        const float4* rowbase = emb4 + (size_t)(f * C) * 16 + t;
        #pragma unroll
        for (int cc = 0; cc < 16; ++cc) {
            const int c   = g * 16 + cc;
            const int idx = __shfl(idxreg, c);
            float4 w = rowbase[idx * 16];
            s.x += w.x; s.y += w.y; s.z += w.z; s.w += w.w;
            sq.x = fmaf(w.x, w.x, sq.x);
            sq.y = fmaf(w.y, w.y, sq.y);
            sq.z = fmaf(w.z, w.z, sq.z);
            sq.w = fmaf(w.w, w.w, sq.w);
        }
    }
    if (lane < D) lin = fmaf(dense[b * D + lane], lin_W[F + lane], lin);
    #pragma unroll
    for (int m = 32; m >= 1; m >>= 1) lin += __shfl_xor(lin, m);
    #pragma unroll
    for (int m = 16; m <= 32; m <<= 1) {
        s.x += __shfl_xor(s.x, m); s.y += __shfl_xor(s.y, m);
        s.z += __shfl_xor(s.z, m); s.w += __shfl_xor(s.w, m);
    }
    float sql = sq.x + sq.y + sq.z + sq.w;
    #pragma unroll
    for (int m = 32; m >= 1; m >>= 1) sql += __shfl_xor(sql, m);
    float s2 = s.x * s.x + s.y * s.y + s.z * s.z + s.w * s.w;
    #pragma unroll
    for (int m = 8; m >= 1; m >>= 1) s2 += __shfl_xor(s2, m);
    if (lane == 0) {
        const float pair = 0.5f * (s2 - sql);
        const float x = lin + lin_b[0] + pair;
        out[b] = 1.f / (1.f + expf(-x));
    }
}

extern "C" void kernel_launch(void* const* d_in, const int* in_sizes, int n_in,
                              void* d_out, int out_size, void* d_ws, size_t ws_size,
                              hipStream_t stream) {
    const int*   sparse  = (const int*)  d_in[0];
    const float* dense   = (const float*)d_in[1];
    const float* lin_emb = (const float*)d_in[2];
    const float* emb_tab = (const float*)d_in[3];
    const float* lin_W   = (const float*)d_in[4];
    const float* lin_b   = (const float*)d_in[5];
    float* out = (float*)d_out;

    if (ws_size < WS_NEED) {
        dim3 grid((B + 3) / 4), block(256);
        hipLaunchKernelGGL(dfm_fallback, grid, block, 0, stream,
                           sparse, dense, lin_emb, emb_tab, lin_W, lin_b, out);
        return;
    }

    char* ws = (char*)d_ws;
    __hip_bfloat16* cnt = (__hip_bfloat16*)(ws + CNT_OFF);
    __hip_bfloat16* bt  = (__hip_bfloat16*)(ws + BT_OFF);
    float*          lin = (float*)(ws + LIN_OFF);
    float*          prt = (float*)(ws + PART_OFF);

    hipLaunchKernelGGL(prep_bt_kernel,  dim3(F),        dim3(256), 0, stream, emb_tab, bt);
    hipLaunchKernelGGL(hist_lin_kernel, dim3(B),        dim3(256), 0, stream,
                       sparse, dense, lin_emb, lin_W, lin_b, cnt, lin);
    hipLaunchKernelGGL(gemm_kernel,     dim3(64 * KSPLIT), dim3(256), 0, stream, cnt, bt, prt);
    hipLaunchKernelGGL(reduce_kernel,   dim3(B / 4),    dim3(256), 0, stream, prt, lin, out);
}

// Round 3
// 28.940 us; speedup vs baseline: 1.3840x; 1.0184x over previous
//
#include <hip/hip_runtime.h>
#include <hip/hip_bf16.h>
#include <math.h>

// Problem constants
#define B 2048
#define F 26
#define C 64
#define E 64
#define D 13
#define SPARSE_W (F * (C + 1) - 1)   // 1689
#define K (F * C)                    // 1664
#define N2 128                       // 64 S cols | 64 SQ cols
#define MT 16                        // samples per block
#define ROWW 836                     // dwords per LDS count row (3344 B, 3344%128==16)

typedef short short8 __attribute__((ext_vector_type(8)));
typedef float f32x4  __attribute__((ext_vector_type(4)));

#define WS_NEED ((size_t)K * N2 * 2)   // Bt only: 425,984 B

// ---------------------------------------------------------------------------
// Kernel 1: build Bt[n][k] bf16, n<64: emb[k,e=n]; n>=64: emb[k,e=n-64]^2
__global__ __launch_bounds__(256) void prep_bt_kernel(
    const float* __restrict__ emb_tab, __hip_bfloat16* __restrict__ bt)
{
    __shared__ float tile[64][65];
    const int f = blockIdx.x;
    const float* src = emb_tab + (size_t)f * 4096;   // [v][e]
    for (int i = threadIdx.x; i < 4096; i += 256)
        tile[i >> 6][i & 63] = src[i];
    __syncthreads();
    const int v  = threadIdx.x & 63;
    const int ns = threadIdx.x >> 6;   // 0..3
    for (int it = 0; it < 32; ++it) {
        const int n = ns * 32 + it;    // 0..127
        float val = tile[v][n & 63];
        if (n >= 64) val = val * val;
        bt[(size_t)n * K + f * 64 + v] = __float2bfloat16(val);
    }
}

// ---------------------------------------------------------------------------
// Fused: LDS u16 histogram -> bf16 -> MFMA GEMM vs Bt -> pairwise+linear+sigmoid
__global__ __launch_bounds__(512) void fused_kernel(
    const int*   __restrict__ sparse,
    const float* __restrict__ dense,
    const float* __restrict__ lin_emb,
    const float* __restrict__ lin_W,
    const float* __restrict__ lin_b,
    const __hip_bfloat16* __restrict__ bt,
    float* __restrict__ out)
{
    __shared__ unsigned int cnt[MT * ROWW];   // 53,504 B
    __shared__ float lin_lds[MT];
    __shared__ float pair_lds[MT];

    const int tid  = threadIdx.x;
    const int lane = tid & 63;
    const int w    = tid >> 6;          // wave 0..7
    const int b0   = blockIdx.x * MT;

    for (int i = tid; i < MT * ROWW; i += 512) cnt[i] = 0;
    if (tid < MT) pair_lds[tid] = 0.f;
    __syncthreads();

    // ---- phase 1: u16 histogram + linear term. wave w owns rows w, w+8.
    const int r0 = w, r1 = w + 8;
    const int* sp0 = sparse + (size_t)(b0 + r0) * SPARSE_W + lane;
    const int* sp1 = sparse + (size_t)(b0 + r1) * SPARSE_W + lane;
    int idx0[F], idx1[F];
    #pragma unroll
    for (int f = 0; f < F; ++f) idx0[f] = sp0[f * (C + 1)];
    #pragma unroll
    for (int f = 0; f < F; ++f) idx1[f] = sp1[f * (C + 1)];

    float lin0 = 0.f, lin1 = 0.f;
    #pragma unroll
    for (int f = 0; f < F; ++f) {
        const int k0 = f * 64 + idx0[f];
        const int k1 = f * 64 + idx1[f];
        atomicAdd(&cnt[r0 * ROWW + (k0 >> 1)], 1u << (16 * (k0 & 1)));
        atomicAdd(&cnt[r1 * ROWW + (k1 >> 1)], 1u << (16 * (k1 & 1)));
        lin0 = fmaf(lin_W[f], lin_emb[f * 64 + idx0[f]], lin0);
        lin1 = fmaf(lin_W[f], lin_emb[f * 64 + idx1[f]], lin1);
    }
    #pragma unroll
    for (int m = 32; m >= 1; m >>= 1) {
        lin0 += __shfl_xor(lin0, m);
        lin1 += __shfl_xor(lin1, m);
    }
    if (lane == 0) { lin_lds[r0] = lin0; lin_lds[r1] = lin1; }
    __syncthreads();

    // ---- phase 1.5: convert u16 counts -> bf16 in place (ints <=64 exact)
    {
        const int row = tid >> 5;          // 16 rows x 32 threads
        const int cl  = tid & 31;
        unsigned int* rp = &cnt[row * ROWW];
        #pragma unroll
        for (int it = 0; it < 26; ++it) {  // 832 used dwords per row
            const int j = cl + it * 32;
            const unsigned int v = rp[j];
            const float flo = (float)(v & 0xffffu);
            const float fhi = (float)(v >> 16);
            rp[j] = (__float_as_uint(fhi) & 0xffff0000u) | (__float_as_uint(flo) >> 16);
        }
    }
    __syncthreads();

    // ---- phase 2: GEMM 16 x 128 x 1664. A: LDS bf16 count; B: Bt (L2).
    // wave w -> cols [16w, 16w+16). A-frag: row=l&15, k=(l>>4)*8+j (16B).
    f32x4 acc_a = {0.f, 0.f, 0.f, 0.f};
    f32x4 acc_b = {0.f, 0.f, 0.f, 0.f};
    const char*  abase = (const char*)cnt + (lane & 15) * (ROWW * 4) + (lane >> 4) * 16;
    const short* pb    = (const short*)bt + (size_t)(w * 16 + (lane & 15)) * K + (lane >> 4) * 8;
    #pragma unroll 4
    for (int kk = 0; kk < 52; kk += 2) {
        short8 a0 = *(const short8*)(abase + (size_t)kk * 64);
        short8 b0v = *(const short8*)(pb + (size_t)kk * 32);
        short8 a1 = *(const short8*)(abase + (size_t)(kk + 1) * 64);
        short8 b1v = *(const short8*)(pb + (size_t)(kk + 1) * 32);
        acc_a = __builtin_amdgcn_mfma_f32_16x16x32_bf16(a0, b0v, acc_a, 0, 0, 0);
        acc_b = __builtin_amdgcn_mfma_f32_16x16x32_bf16(a1, b1v, acc_b, 0, 0, 0);
    }

    // ---- epilogue: pair[row] += sum_cols (S^2) and (-SQ)
    #pragma unroll
    for (int r = 0; r < 4; ++r) {
        const float v = acc_a[r] + acc_b[r];
        float c = (w < 4) ? v * v : -v;
        c += __shfl_xor(c, 1);
        c += __shfl_xor(c, 2);
        c += __shfl_xor(c, 4);
        c += __shfl_xor(c, 8);
        if ((lane & 15) == 0)
            atomicAdd(&pair_lds[(lane >> 4) * 4 + r], c);
    }
    __syncthreads();

    if (tid < MT) {
        const int row = tid;
        float x = lin_lds[row] + lin_b[0] + 0.5f * pair_lds[row];
        const float* dp = dense + (size_t)(b0 + row) * D;
        #pragma unroll
        for (int j = 0; j < D; ++j) x = fmaf(dp[j], lin_W[F + j], x);
        out[b0 + row] = 1.f / (1.f + expf(-x));
    }
}

// ---------------------------------------------------------------------------
// Fallback (round-1 kernel) if ws is too small.
__global__ __launch_bounds__(256) void dfm_fallback(
    const int*   __restrict__ sparse,
    const float* __restrict__ dense,
    const float* __restrict__ lin_emb,
    const float* __restrict__ emb_tab,
    const float* __restrict__ lin_W,
    const float* __restrict__ lin_b,
    float*       __restrict__ out)
{
    const int lane = threadIdx.x & 63;
    const int wv   = threadIdx.x >> 6;
    const int b    = blockIdx.x * 4 + wv;
    if (b >= B) return;
    const int g = lane >> 4;
    const int t = lane & 15;
    const float4* emb4 = reinterpret_cast<const float4*>(emb_tab);
    float4 s  = make_float4(0.f, 0.f, 0.f, 0.f);
    float4 sq = make_float4(0.f, 0.f, 0.f, 0.f);
    float  lin = 0.f;
    const int sbase = b * SPARSE_W;
    for (int f = 0; f < F; ++f) {
        int idxreg = sparse[sbase + f * (C + 1) + lane];
        lin = fmaf(lin_W[f], lin_emb[f * C + idxreg], lin);
        const float4* rowbase = emb4 + (size_t)(f * C) * 16 + t;
        #pragma unroll
        for (int cc = 0; cc < 16; ++cc) {
            const int c   = g * 16 + cc;
            const int idx = __shfl(idxreg, c);
            float4 w = rowbase[idx * 16];
            s.x += w.x; s.y += w.y; s.z += w.z; s.w += w.w;
            sq.x = fmaf(w.x, w.x, sq.x);
            sq.y = fmaf(w.y, w.y, sq.y);
            sq.z = fmaf(w.z, w.z, sq.z);
            sq.w = fmaf(w.w, w.w, sq.w);
        }
    }
    if (lane < D) lin = fmaf(dense[b * D + lane], lin_W[F + lane], lin);
    #pragma unroll
    for (int m = 32; m >= 1; m >>= 1) lin += __shfl_xor(lin, m);
    #pragma unroll
    for (int m = 16; m <= 32; m <<= 1) {
        s.x += __shfl_xor(s.x, m); s.y += __shfl_xor(s.y, m);
        s.z += __shfl_xor(s.z, m); s.w += __shfl_xor(s.w, m);
    }
    float sql = sq.x + sq.y + sq.z + sq.w;
    #pragma unroll
    for (int m = 32; m >= 1; m >>= 1) sql += __shfl_xor(sql, m);
    float s2 = s.x * s.x + s.y * s.y + s.z * s.z + s.w * s.w;
    #pragma unroll
    for (int m = 8; m >= 1; m >>= 1) s2 += __shfl_xor(s2, m);
    if (lane == 0) {
        const float pair = 0.5f * (s2 - sql);
        const float x = lin + lin_b[0] + pair;
        out[b] = 1.f / (1.f + expf(-x));
    }
}

extern "C" void kernel_launch(void* const* d_in, const int* in_sizes, int n_in,
                              void* d_out, int out_size, void* d_ws, size_t ws_size,
                              hipStream_t stream) {
    const int*   sparse  = (const int*)  d_in[0];
    const float* dense   = (const float*)d_in[1];
    const float* lin_emb = (const float*)d_in[2];
    const float* emb_tab = (const float*)d_in[3];
    const float* lin_W   = (const float*)d_in[4];
    const float* lin_b   = (const float*)d_in[5];
    float* out = (float*)d_out;

    if (ws_size < WS_NEED) {
        dim3 grid((B + 3) / 4), block(256);
        hipLaunchKernelGGL(dfm_fallback, grid, block, 0, stream,
                           sparse, dense, lin_emb, emb_tab, lin_W, lin_b, out);
        return;
    }

    __hip_bfloat16* bt = (__hip_bfloat16*)d_ws;

    hipLaunchKernelGGL(prep_bt_kernel, dim3(F),      dim3(256), 0, stream, emb_tab, bt);
    hipLaunchKernelGGL(fused_kernel,   dim3(B / MT), dim3(512), 0, stream,
                       sparse, dense, lin_emb, lin_W, lin_b, bt, out);
}